// Round 1
// baseline (112.725 us; speedup 1.0000x reference)
//
#include <hip/hip_runtime.h>
#include <cstdint>

// BFP quantize: block = channel vector at each (n,h,w), NCHW layout.
// N=64, C=256, H=W=56. mantissa_bits=3.
// delta = 2^(e-3) where max_abs = m*2^e, m in [0.5,1)  (frexp convention).
// q = trunc(x/delta)*delta — all exact power-of-two arithmetic.

constexpr int C    = 256;
constexpr int HW   = 56 * 56;   // 3136
constexpr int HW4  = HW / 4;    // 784 float4 per (n,c) plane row-block
constexpr int CHW4 = C * HW4;   // float4 per image

__device__ __forceinline__ int fexp(float x) {
    int e;
    (void)frexpf(x, &e);        // v_frexp_exp_i32_f32; e=0 for x==0
    return e;
}

__global__ __launch_bounds__(64) void bfp_kernel(const float4* __restrict__ in,
                                                 float4* __restrict__ out,
                                                 int total) {
    int t = blockIdx.x * 64 + threadIdx.x;
    if (t >= total) return;
    int n  = t / HW4;
    int s4 = t - n * HW4;

    const float4* p = in  + (size_t)n * CHW4 + s4;
    float4*       q = out + (size_t)n * CHW4 + s4;

    // ---- pass 1: per-lane (4 spatial sites) max |x| over 256 channels ----
    float4 m = make_float4(0.f, 0.f, 0.f, 0.f);
#pragma unroll 8
    for (int c = 0; c < C; ++c) {
        float4 v = p[c * HW4];
        m.x = fmaxf(m.x, fabsf(v.x));
        m.y = fmaxf(m.y, fabsf(v.y));
        m.z = fmaxf(m.z, fabsf(v.z));
        m.w = fmaxf(m.w, fabsf(v.w));
    }

    // ---- shared exponent -> delta (2^(e-3)) and exact inverse (2^(3-e)) ----
    int ex = fexp(m.x), ey = fexp(m.y), ez = fexp(m.z), ew = fexp(m.w);
    float dx = ldexpf(1.f, ex - 3), ix = ldexpf(1.f, 3 - ex);
    float dy = ldexpf(1.f, ey - 3), iy = ldexpf(1.f, 3 - ey);
    float dz = ldexpf(1.f, ez - 3), iz = ldexpf(1.f, 3 - ez);
    float dw = ldexpf(1.f, ew - 3), iw = ldexpf(1.f, 3 - ew);

    // ---- pass 2: quantize (second read mostly L3-resident) ----
#pragma unroll 8
    for (int c = 0; c < C; ++c) {
        float4 v = p[c * HW4];
        float4 r;
        r.x = truncf(v.x * ix) * dx;
        r.y = truncf(v.y * iy) * dy;
        r.z = truncf(v.z * iz) * dz;
        r.w = truncf(v.w * iw) * dw;
        q[c * HW4] = r;
    }
}

extern "C" void kernel_launch(void* const* d_in, const int* in_sizes, int n_in,
                              void* d_out, int out_size, void* d_ws, size_t ws_size,
                              hipStream_t stream) {
    const float* in = (const float*)d_in[0];
    float* out      = (float*)d_out;
    int N     = in_sizes[0] / (C * HW);   // 64
    int total = N * HW4;                  // 50176 threads, 4 spatial sites each
    dim3 grid((total + 63) / 64);
    bfp_kernel<<<grid, 64, 0, stream>>>((const float4*)in, (float4*)out, total);
}

// Round 2
// 92.514 us; speedup vs baseline: 1.2185x; 1.2185x over previous
//
#include <hip/hip_runtime.h>
#include <cstdint>

// BFP quantize: block = channel vector at each (n,h,w), NCHW layout.
// N=64, C=256, H=W=56, mantissa_bits=3.
// delta = 2^(e-3) where max_abs = m*2^e, m in [0.5,1)  (frexp convention).
// q = trunc(x/delta)*delta — exact power-of-two arithmetic (absmax==0 verified R1).
//
// Wave decomposition (R2): lane l -> site s = wave*4 + (l&3), chunk k = l>>2.
// Each lane: 16 channels in registers; shfl_xor butterfly (masks 4..32) reduces
// abs-max across the 16 lanes sharing a site. No LDS, no barriers, single
// global read (quantize from registers) + single write.

constexpr int C     = 256;
constexpr int HW    = 56 * 56;   // 3136
constexpr int HW4   = HW / 4;    // 784 float4 per (n,c) plane
constexpr int CHW4  = C * HW4;   // float4 per image
constexpr int CHUNK = 16;        // channels per lane (16 lanes cover C=256)

__device__ __forceinline__ int fexp(float x) {
    int e;
    (void)frexpf(x, &e);         // v_frexp_exp_i32_f32; e=0 for x==0
    return e;
}

__global__ __launch_bounds__(256, 4)
void bfp_kernel(const float4* __restrict__ in, float4* __restrict__ out, int total4) {
    int tid  = blockIdx.x * 256 + threadIdx.x;
    int wave = tid >> 6;
    int lane = threadIdx.x & 63;
    int s    = wave * 4 + (lane & 3);     // float4 spatial-site index
    if (s >= total4) return;
    int k    = lane >> 2;                 // channel chunk 0..15

    int n  = s / HW4;
    int s4 = s - n * HW4;

    const float4* p = in  + (size_t)n * CHW4 + (size_t)k * CHUNK * HW4 + s4;
    float4*       q = out + (size_t)n * CHW4 + (size_t)k * CHUNK * HW4 + s4;

    // ---- load 16 channels into registers, partial abs-max ----
    float4 v[CHUNK];
#pragma unroll
    for (int i = 0; i < CHUNK; ++i) v[i] = p[i * HW4];

    float4 m = make_float4(0.f, 0.f, 0.f, 0.f);
#pragma unroll
    for (int i = 0; i < CHUNK; ++i) {
        m.x = fmaxf(m.x, fabsf(v[i].x));
        m.y = fmaxf(m.y, fabsf(v[i].y));
        m.z = fmaxf(m.z, fabsf(v[i].z));
        m.w = fmaxf(m.w, fabsf(v[i].w));
    }

    // ---- butterfly reduce across the 16 lanes sharing this site ----
#pragma unroll
    for (int mask = 4; mask < 64; mask <<= 1) {
        m.x = fmaxf(m.x, __shfl_xor(m.x, mask));
        m.y = fmaxf(m.y, __shfl_xor(m.y, mask));
        m.z = fmaxf(m.z, __shfl_xor(m.z, mask));
        m.w = fmaxf(m.w, __shfl_xor(m.w, mask));
    }

    // ---- shared exponent -> delta = 2^(e-3), inv = 2^(3-e) (both exact) ----
    int ex = fexp(m.x), ey = fexp(m.y), ez = fexp(m.z), ew = fexp(m.w);
    float dx = ldexpf(1.f, ex - 3), ix = ldexpf(1.f, 3 - ex);
    float dy = ldexpf(1.f, ey - 3), iy = ldexpf(1.f, 3 - ey);
    float dz = ldexpf(1.f, ez - 3), iz = ldexpf(1.f, 3 - ez);
    float dw = ldexpf(1.f, ew - 3), iw = ldexpf(1.f, 3 - ew);

    // ---- quantize from registers, store ----
#pragma unroll
    for (int i = 0; i < CHUNK; ++i) {
        float4 r;
        r.x = truncf(v[i].x * ix) * dx;
        r.y = truncf(v[i].y * iy) * dy;
        r.z = truncf(v[i].z * iz) * dz;
        r.w = truncf(v[i].w * iw) * dw;
        q[i * HW4] = r;
    }
}

extern "C" void kernel_launch(void* const* d_in, const int* in_sizes, int n_in,
                              void* d_out, int out_size, void* d_ws, size_t ws_size,
                              hipStream_t stream) {
    const float* in = (const float*)d_in[0];
    float* out      = (float*)d_out;
    int N      = in_sizes[0] / (C * HW);        // 64
    int total4 = N * HW4;                       // 50176 float4 sites
    int waves  = (total4 + 3) / 4;              // 4 sites per wave
    int blocks = (waves + 3) / 4;               // 4 waves per 256-thread block
    bfp_kernel<<<blocks, 256, 0, stream>>>((const float4*)in, (float4*)out, total4);
}